// Round 9
// baseline (142.454 us; speedup 1.0000x reference)
//
#include <hip/hip_runtime.h>
#include <hip/hip_bf16.h>
#include <math.h>

// Problem constants
constexpr int Bb = 32;
constexpr int Ll = 1024;
constexpr int DC = 1024;
constexpr int DQ = 1024;
constexpr int Hh = 512;
#define NEG_NUM -10000.0f

typedef __attribute__((ext_vector_type(8))) short bf16x8;
typedef __attribute__((ext_vector_type(4))) float f32x4;

#define GLOAD_LDS16(g, l)                                                  \
    __builtin_amdgcn_global_load_lds(                                      \
        (const __attribute__((address_space(1))) void*)(g),                \
        (__attribute__((address_space(3))) void*)(l), 16, 0, 0)

__device__ inline unsigned short f2bf(float f) {           // RNE f32->bf16
    unsigned int x = __float_as_uint(f);
    unsigned int r = (x + 0x7FFFu + ((x >> 16) & 1u)) >> 16;
    return (unsigned short)r;
}
__device__ inline float bfu(unsigned short u) {            // bf16 bits -> f32 (exact)
    return __uint_as_float(((unsigned int)u) << 16);
}

// SWIZZLE (unchanged from R8, verified): bf16 buffers store element (row, k)
// at k ^ ((row&7)<<3) within each 64-elem block; consumers XOR on read.

// ---------------------------------------------------------------------------
// prep, 18816 blocks:
//   [0,2048):        W1[:DC] -> w1t bf16 (512x1024 transposed, swz)
//   [2048,2176):     zero out_ctx AND score
//   [2176,2432):     qb[b,h] = query[b,:] @ W1[DC:,h] + b1[h]
//   [2432,18816):    ctx fp32 -> ctxb bf16 (swizzled store), 8 elem/thread
// ---------------------------------------------------------------------------
__global__ __launch_bounds__(256) void prep_kernel(const float* __restrict__ W1,
                                                   const float* __restrict__ query,
                                                   const float* __restrict__ b1,
                                                   const float* __restrict__ ctx,
                                                   unsigned short* __restrict__ w1t,
                                                   float* __restrict__ qb,
                                                   float* __restrict__ score,
                                                   float* __restrict__ out_ctx,
                                                   unsigned short* __restrict__ ctxb) {
    __shared__ float red[4][64];
    const int bid = blockIdx.x;
    if (bid < 2048) {
        int idx = bid * 256 + threadIdx.x;   // n*1024 + k
        int n = idx >> 10, k = idx & 1023;
        int ks = k ^ ((n & 7) << 3);
        w1t[(size_t)n * 1024 + ks] = f2bf(W1[(size_t)k * Hh + n]);
    } else if (bid < 2176) {
        int i = (bid - 2048) * 256 + threadIdx.x;
        out_ctx[i] = 0.f;
        score[i] = 0.f;
    } else if (bid < 2432) {
        const int qbid = bid - 2176;          // 0..255
        const int b  = qbid >> 3;
        const int hg = qbid & 7;
        const int hl = threadIdx.x & 63;
        const int j  = threadIdx.x >> 6;
        const int h  = hg * 64 + hl;
        const float* q = query + (size_t)b * DQ + j * 256;
        const float* w = W1 + (size_t)(DC + j * 256) * Hh + h;
        float a0 = 0.f, a1 = 0.f, a2 = 0.f, a3 = 0.f;
#pragma unroll 4
        for (int c = 0; c < 256; c += 4) {
            a0 += q[c + 0] * w[(size_t)(c + 0) * Hh];
            a1 += q[c + 1] * w[(size_t)(c + 1) * Hh];
            a2 += q[c + 2] * w[(size_t)(c + 2) * Hh];
            a3 += q[c + 3] * w[(size_t)(c + 3) * Hh];
        }
        red[j][hl] = (a0 + a1) + (a2 + a3);
        __syncthreads();
        if (j == 0)
            qb[(size_t)b * Hh + h] = red[0][hl] + red[1][hl] + red[2][hl] + red[3][hl] + b1[h];
    } else {
        size_t i = (size_t)((bid - 2432) * 256 + threadIdx.x) * 8;
        int row = (int)(i >> 10);
        int col = (int)(i & 1023);
        float4 v0 = *(const float4*)(ctx + i);
        float4 v1 = *(const float4*)(ctx + i + 4);
        union { unsigned short us[8]; uint4 v; } o;
        o.us[0] = f2bf(v0.x); o.us[1] = f2bf(v0.y); o.us[2] = f2bf(v0.z); o.us[3] = f2bf(v0.w);
        o.us[4] = f2bf(v1.x); o.us[5] = f2bf(v1.y); o.us[6] = f2bf(v1.z); o.us[7] = f2bf(v1.w);
        *(uint4*)(ctxb + ((size_t)row << 10) + (col ^ ((row & 7) << 3))) = o.v;
    }
}

// ---------------------------------------------------------------------------
// Barrier-free split-K MFMA GEMM + tanh + w2 reduction.
//   Block: 64x64 output tile, 4 waves. Wave wv owns K in [wv*256, wv*256+256)
//   and an EXCLUSIVE 16 KB LDS region (A 8 KB + B 8 KB, single-buffered).
//   Per BK=64 chunk: 16 fire-and-forget global_load_lds -> s_waitcnt vmcnt(0)
//   (same-wave LDS visibility, NO barrier) -> 16 swizzled ds_read_b128 ->
//   32 MFMA. Waves drift freely: one wave's load-drain overlaps another's
//   MFMA burst (m114 mechanism, no lockstep barrier throttle).
//   One __syncthreads total: cross-wave partial-C reduce via LDS, then
//   tanh+w2 row-reduce -> atomicAdd score (8 n-blocks per row).
//   64 KB LDS -> 2 blocks/CU = 8 waves/CU. Grid (8,512) n-fast: same-A-panel
//   siblings temporally adjacent -> L2/L3-served re-reads.
// ---------------------------------------------------------------------------
__global__ __launch_bounds__(256) void gemm_splitk(const unsigned short* __restrict__ ctxb,
                                                   const unsigned short* __restrict__ w1t,
                                                   const float* __restrict__ qb,
                                                   const float* __restrict__ w2,
                                                   float* __restrict__ score) {
    __shared__ char lds[4 * 16384];          // wave wv owns [wv*16K, wv*16K+16K)

    const int n0 = blockIdx.x * 64;
    const int m0 = blockIdx.y * 64;
    const int tid = threadIdx.x;
    const int wv = tid >> 6, lane = tid & 63;
    const int lr = lane & 15, lk = lane >> 4;

    char* base = lds + wv * 16384;
    const char* ctxB = (const char*)ctxb;
    const char* w1tB = (const char*)w1t;

    const int srow = lane >> 3;              // staging: 8 rows per issue
    const int scolb = (lane & 7) * 16;
    const int x = (lr & 7) << 4;             // fragment read XOR

    f32x4 acc[4][4];
#pragma unroll
    for (int mf = 0; mf < 4; ++mf)
#pragma unroll
        for (int nf = 0; nf < 4; ++nf) acc[mf][nf] = (f32x4){0.f, 0.f, 0.f, 0.f};

    for (int c = 0; c < 4; ++c) {
        const int k0 = wv * 256 + c * 64;    // this wave's K-chunk
        __builtin_amdgcn_sched_barrier(0);   // keep stage below prior reads
        // ---- stage A(64x64) + B(64x64) bf16, linear copy of swz buffers ----
#pragma unroll
        for (int i = 0; i < 8; ++i) {
            int row = i * 8 + srow;
            GLOAD_LDS16(ctxB + (size_t)(m0 + row) * 2048 + k0 * 2 + scolb,
                        base + i * 1024 + lane * 16);
            GLOAD_LDS16(w1tB + (size_t)(n0 + row) * 2048 + k0 * 2 + scolb,
                        base + 8192 + i * 1024 + lane * 16);
        }
        asm volatile("s_waitcnt vmcnt(0)" ::: "memory");   // own DMA landed
        __builtin_amdgcn_sched_barrier(0);
        // ---- compute: 2 k-halves x (8 ds_read_b128 + 16 MFMA) ----
#pragma unroll
        for (int kk = 0; kk < 2; ++kk) {
            const int colb = (kk * 64 + lk * 16) ^ x;
            bf16x8 a[4], bb[4];
#pragma unroll
            for (int mf = 0; mf < 4; ++mf)
                a[mf] = *(const bf16x8*)(base + (mf * 16 + lr) * 128 + colb);
#pragma unroll
            for (int nf = 0; nf < 4; ++nf)
                bb[nf] = *(const bf16x8*)(base + 8192 + (nf * 16 + lr) * 128 + colb);
#pragma unroll
            for (int mf = 0; mf < 4; ++mf)
#pragma unroll
                for (int nf = 0; nf < 4; ++nf)
                    acc[mf][nf] = __builtin_amdgcn_mfma_f32_16x16x32_bf16(a[mf], bb[nf], acc[mf][nf], 0, 0, 0);
        }
    }

    // ---- cross-wave reduce: write partials to own region, one barrier ----
#pragma unroll
    for (int mf = 0; mf < 4; ++mf)
#pragma unroll
        for (int nf = 0; nf < 4; ++nf)
            *(f32x4*)(base + (mf * 4 + nf) * 1024 + lane * 16) = acc[mf][nf];
    __syncthreads();

    // wave wv reduces row-group mf = wv (rows m0 + wv*16 + lk*4 + r)
    const float* qbb = qb + (size_t)(m0 >> 10) * Hh;
    float s0 = 0.f, s1 = 0.f, s2 = 0.f, s3 = 0.f;
#pragma unroll
    for (int nf = 0; nf < 4; ++nf) {
        f32x4 t = (f32x4){0.f, 0.f, 0.f, 0.f};
#pragma unroll
        for (int w = 0; w < 4; ++w)
            t += *(const f32x4*)(lds + w * 16384 + (wv * 4 + nf) * 1024 + lane * 16);
        int col = n0 + nf * 16 + lr;
        float wvw = w2[col];
        float qv = qbb[col];
        s0 += tanhf(t[0] + qv) * wvw;
        s1 += tanhf(t[1] + qv) * wvw;
        s2 += tanhf(t[2] + qv) * wvw;
        s3 += tanhf(t[3] + qv) * wvw;
    }
#pragma unroll
    for (int off = 8; off; off >>= 1) {
        s0 += __shfl_xor(s0, off, 16);
        s1 += __shfl_xor(s1, off, 16);
        s2 += __shfl_xor(s2, off, 16);
        s3 += __shfl_xor(s3, off, 16);
    }
    if (lr == 0) {
        int row = m0 + wv * 16 + lk * 4;
        atomicAdd(&score[row + 0], s0);
        atomicAdd(&score[row + 1], s1);
        atomicAdd(&score[row + 2], s2);
        atomicAdd(&score[row + 3], s3);
    }
}

// ---------------------------------------------------------------------------
// scan: p = sigmoid(score + b2, masked, + noise); att_l = p_l * prod_{i<l}(1-p_i)
// ---------------------------------------------------------------------------
__global__ __launch_bounds__(64) void scan_kernel(const float* __restrict__ score,
                                                  const int* __restrict__ mask,
                                                  const float* __restrict__ noise,
                                                  const float* __restrict__ b2p,
                                                  float* __restrict__ att) {
    int b = blockIdx.x;
    int lane = threadIdx.x;
    float b2 = b2p[0];
    int base = b * Ll + lane * 16;

    float p[16], q[16];
    float run = 1.f;
#pragma unroll
    for (int j = 0; j < 16; ++j) {
        int l = base + j;
        float s = score[l] + b2;
        if (mask[l] == 0) s = NEG_NUM;
        s += noise[l];
        float pv = 1.f / (1.f + expf(-s));
        p[j] = pv;
        run *= (1.f - pv);
        q[j] = run;
    }
    float incl = run;
#pragma unroll
    for (int off = 1; off < 64; off <<= 1) {
        float v = __shfl_up(incl, off, 64);
        if (lane >= off) incl *= v;
    }
    float excl = __shfl_up(incl, 1, 64);
    if (lane == 0) excl = 1.f;
#pragma unroll
    for (int j = 0; j < 16; ++j) {
        float P = excl * (j == 0 ? 1.f : q[j - 1]);
        att[base + j] = p[j] * P;
    }
}

// ---------------------------------------------------------------------------
// expected_ctx[b,c] = sum_l att[b,l] * ctx[b,l,c]  (swz bf16 ctxb, 4 c/thread)
// ---------------------------------------------------------------------------
__global__ __launch_bounds__(256) void ectx_bf16_kernel(const unsigned short* __restrict__ ctxb,
                                                        const float* __restrict__ att,
                                                        float* __restrict__ out) {
    int b = blockIdx.z;
    int c4 = threadIdx.x;                 // c = c4*4
    int l0 = blockIdx.y * 128;
    const unsigned short* cb = ctxb + ((size_t)b * Ll + l0) * DC;
    const float* ab = att + (size_t)b * Ll + l0;
    const int c = c4 * 4;
    float a0 = 0.f, a1 = 0.f, a2 = 0.f, a3 = 0.f;
    for (int l = 0; l < 128; ++l) {
        float av = ab[l];
        int cs = c ^ ((l & 7) << 3);
        ushort4 v = *(const ushort4*)(cb + (size_t)l * DC + cs);
        a0 += av * bfu(v.x); a1 += av * bfu(v.y);
        a2 += av * bfu(v.z); a3 += av * bfu(v.w);
    }
    float* o = out + (size_t)b * DC + c;
    atomicAdd(o + 0, a0); atomicAdd(o + 1, a1);
    atomicAdd(o + 2, a2); atomicAdd(o + 3, a3);
}

// ---------------------------------------------------------------------------
extern "C" void kernel_launch(void* const* d_in, const int* in_sizes, int n_in,
                              void* d_out, int out_size, void* d_ws, size_t ws_size,
                              hipStream_t stream) {
    const float* ctx   = (const float*)d_in[0];
    const float* query = (const float*)d_in[1];
    const int*   mask  = (const int*)d_in[2];
    const float* noise = (const float*)d_in[3];
    const float* W1    = (const float*)d_in[4];
    const float* b1    = (const float*)d_in[5];
    const float* w2    = (const float*)d_in[6];
    const float* b2    = (const float*)d_in[7];

    float* out_ctx = (float*)d_out;                 // [B, DC]
    float* out_att = (float*)d_out + Bb * DC;       // [B, L]

    char* ws = (char*)d_ws;
    float* score = (float*)ws;                                   // 131072 B
    float* qb    = (float*)(ws + 131072);                        //  65536 B
    unsigned short* w1t  = (unsigned short*)(ws + 196608);       // 1 MiB
    unsigned short* ctxb = (unsigned short*)(ws + 1245184);      // 64 MiB

    // w1t transpose-cvt (swz) + zeros + qb + ctx->bf16 (one kernel)
    prep_kernel<<<18816, 256, 0, stream>>>(W1, query, b1, ctx, w1t, qb, score, out_ctx, ctxb);

    // barrier-free split-K MFMA GEMM + tanh + w2 -> score
    gemm_splitk<<<dim3(Hh / 64, (Bb * Ll) / 64), 256, 0, stream>>>(ctxb, w1t, qb, w2, score);

    // sigmoid/mask/noise/scan -> att (second output)
    scan_kernel<<<Bb, 64, 0, stream>>>(score, mask, noise, b2, out_att);

    // expected_ctx = att @ ctx (swz bf16 ctxb, L3-resident)
    ectx_bf16_kernel<<<dim3(1, Ll / 128, Bb), 256, 0, stream>>>(ctxb, out_att, out_ctx);
}

// Round 10
// 100.556 us; speedup vs baseline: 1.4167x; 1.4167x over previous
//
#include <hip/hip_runtime.h>
#include <hip/hip_bf16.h>
#include <math.h>

// Problem constants
constexpr int Bb = 32;
constexpr int Ll = 1024;
constexpr int DC = 1024;
constexpr int DQ = 1024;
constexpr int Hh = 512;
#define NEG_NUM -10000.0f

typedef __attribute__((ext_vector_type(8))) short bf16x8;
typedef __attribute__((ext_vector_type(4))) float f32x4;

#define GLOAD_LDS16(g, l)                                                  \
    __builtin_amdgcn_global_load_lds(                                      \
        (const __attribute__((address_space(1))) void*)(g),                \
        (__attribute__((address_space(3))) void*)(l), 16, 0, 0)

__device__ inline unsigned short f2bf(float f) {           // RNE f32->bf16
    unsigned int x = __float_as_uint(f);
    unsigned int r = (x + 0x7FFFu + ((x >> 16) & 1u)) >> 16;
    return (unsigned short)r;
}
__device__ inline float bfu(unsigned short u) {            // bf16 bits -> f32 (exact)
    return __uint_as_float(((unsigned int)u) << 16);
}

// SWIZZLE (verified R8/R9, conflicts=0): bf16 buffers store element (row, k)
// at k ^ ((row&7)<<3) within each 64-elem k-block; consumers XOR on read.

// ---------------------------------------------------------------------------
// prep, 18816 blocks (verified R9):
//   [0,2048):        W1[:DC] -> w1t bf16 (512x1024 transposed, swz)
//   [2048,2176):     zero out_ctx AND score
//   [2176,2432):     qb[b,h] = query[b,:] @ W1[DC:,h] + b1[h]
//   [2432,18816):    ctx fp32 -> ctxb bf16 (swizzled store), 8 elem/thread
// ---------------------------------------------------------------------------
__global__ __launch_bounds__(256) void prep_kernel(const float* __restrict__ W1,
                                                   const float* __restrict__ query,
                                                   const float* __restrict__ b1,
                                                   const float* __restrict__ ctx,
                                                   unsigned short* __restrict__ w1t,
                                                   float* __restrict__ qb,
                                                   float* __restrict__ score,
                                                   float* __restrict__ out_ctx,
                                                   unsigned short* __restrict__ ctxb) {
    __shared__ float red[4][64];
    const int bid = blockIdx.x;
    if (bid < 2048) {
        int idx = bid * 256 + threadIdx.x;   // n*1024 + k
        int n = idx >> 10, k = idx & 1023;
        int ks = k ^ ((n & 7) << 3);
        w1t[(size_t)n * 1024 + ks] = f2bf(W1[(size_t)k * Hh + n]);
    } else if (bid < 2176) {
        int i = (bid - 2048) * 256 + threadIdx.x;
        out_ctx[i] = 0.f;
        score[i] = 0.f;
    } else if (bid < 2432) {
        const int qbid = bid - 2176;          // 0..255
        const int b  = qbid >> 3;
        const int hg = qbid & 7;
        const int hl = threadIdx.x & 63;
        const int j  = threadIdx.x >> 6;
        const int h  = hg * 64 + hl;
        const float* q = query + (size_t)b * DQ + j * 256;
        const float* w = W1 + (size_t)(DC + j * 256) * Hh + h;
        float a0 = 0.f, a1 = 0.f, a2 = 0.f, a3 = 0.f;
#pragma unroll 4
        for (int c = 0; c < 256; c += 4) {
            a0 += q[c + 0] * w[(size_t)(c + 0) * Hh];
            a1 += q[c + 1] * w[(size_t)(c + 1) * Hh];
            a2 += q[c + 2] * w[(size_t)(c + 2) * Hh];
            a3 += q[c + 3] * w[(size_t)(c + 3) * Hh];
        }
        red[j][hl] = (a0 + a1) + (a2 + a3);
        __syncthreads();
        if (j == 0)
            qb[(size_t)b * Hh + h] = red[0][hl] + red[1][hl] + red[2][hl] + red[3][hl] + b1[h];
    } else {
        size_t i = (size_t)((bid - 2432) * 256 + threadIdx.x) * 8;
        int row = (int)(i >> 10);
        int col = (int)(i & 1023);
        float4 v0 = *(const float4*)(ctx + i);
        float4 v1 = *(const float4*)(ctx + i + 4);
        union { unsigned short us[8]; uint4 v; } o;
        o.us[0] = f2bf(v0.x); o.us[1] = f2bf(v0.y); o.us[2] = f2bf(v0.z); o.us[3] = f2bf(v0.w);
        o.us[4] = f2bf(v1.x); o.us[5] = f2bf(v1.y); o.us[6] = f2bf(v1.z); o.us[7] = f2bf(v1.w);
        *(uint4*)(ctxb + ((size_t)row << 10) + (col ^ ((row & 7) << 3))) = o.v;
    }
}

// ---------------------------------------------------------------------------
// MFMA GEMM + tanh + w2 reduction — 256x256 tile, double-buffered, 1 barrier/step.
//   512 thr / 8 waves (2 M x 4 N); per-wave output 128x64 (mf 0..7, nf 0..3),
//   acc 8x4 f32x4 = 128 AGPR. BK=64, 16 K-steps.
//   Per step: issue stage(K-tile ks+1 -> buf nxt) fire-and-forget (8
//   global_load_lds/thread, LINEAR dest of pre-swizzled global), then compute
//   buf cur (2 kk x (12 ds_read_b128 + 32 MFMA), XOR'd addrs), then ONE
//   __syncthreads (its vmcnt(0) drain + sync protects both buffers).
//   Grid (2,128) = 256 blocks = 1/CU. Score partials via atomicAdd (2 n-blocks).
// ---------------------------------------------------------------------------
__global__ __launch_bounds__(512, 1) void gemm_mfma(const unsigned short* __restrict__ ctxb,
                                                    const unsigned short* __restrict__ w1t,
                                                    const float* __restrict__ qb,
                                                    const float* __restrict__ w2,
                                                    float* __restrict__ score) {
    __shared__ unsigned short lds[2 * 65536 / 2];   // 2 bufs x (A 32K + B 32K)

    const int n0 = blockIdx.x * 256;
    const int m0 = blockIdx.y * 256;
    const int tid = threadIdx.x;
    const int wv = tid >> 6, lane = tid & 63;
    const int wr = wv >> 2, wc = wv & 3;           // 2 M-waves x 4 N-waves
    const int lr = lane & 15, lk = lane >> 4;

    char* ldsB = (char*)lds;
    const char* ctxB = (const char*)ctxb;
    const char* w1tB = (const char*)w1t;

    const int srow = tid >> 3;                     // staging: 64 rows per issue
    const int scolb = (tid & 7) * 16;
    const int x = (lr & 7) << 4;                   // fragment read XOR

    f32x4 acc[8][4];
#pragma unroll
    for (int mf = 0; mf < 8; ++mf)
#pragma unroll
        for (int nf = 0; nf < 4; ++nf) acc[mf][nf] = (f32x4){0.f, 0.f, 0.f, 0.f};

    // ---- prologue: stage K-tile 0 into buf0 ----
#pragma unroll
    for (int i = 0; i < 4; ++i) {
        int row = i * 64 + srow;
        GLOAD_LDS16(ctxB + (size_t)(m0 + row) * 2048 + scolb,
                    ldsB + i * 8192 + tid * 16);
        GLOAD_LDS16(w1tB + (size_t)(n0 + row) * 2048 + scolb,
                    ldsB + 32768 + i * 8192 + tid * 16);
    }
    __syncthreads();

    // ---- main loop: 16 K-steps, ONE barrier each ----
    for (int ks = 0; ks < 16; ++ks) {
        const int cur = ks & 1;
        char* bufc = ldsB + cur * 65536;
        if (ks < 15) {
            char* bufn = ldsB + (cur ^ 1) * 65536;
            const int kb = (ks + 1) * 128;         // byte offset of k0 in row
#pragma unroll
            for (int i = 0; i < 4; ++i) {
                int row = i * 64 + srow;
                GLOAD_LDS16(ctxB + (size_t)(m0 + row) * 2048 + kb + scolb,
                            bufn + i * 8192 + tid * 16);
                GLOAD_LDS16(w1tB + (size_t)(n0 + row) * 2048 + kb + scolb,
                            bufn + 32768 + i * 8192 + tid * 16);
            }
        }
        // compute current buffer: 2 kk x (8+4 ds_read_b128, 32 MFMA)
#pragma unroll
        for (int kk = 0; kk < 2; ++kk) {
            const int colb = (kk * 64 + lk * 16) ^ x;
            bf16x8 a[8], bb[4];
#pragma unroll
            for (int nf = 0; nf < 4; ++nf)
                bb[nf] = *(const bf16x8*)(bufc + 32768 + (wc * 64 + nf * 16 + lr) * 128 + colb);
#pragma unroll
            for (int mf = 0; mf < 8; ++mf)
                a[mf] = *(const bf16x8*)(bufc + (wr * 128 + mf * 16 + lr) * 128 + colb);
#pragma unroll
            for (int mf = 0; mf < 8; ++mf)
#pragma unroll
                for (int nf = 0; nf < 4; ++nf)
                    acc[mf][nf] = __builtin_amdgcn_mfma_f32_16x16x32_bf16(a[mf], bb[nf], acc[mf][nf], 0, 0, 0);
        }
        __syncthreads();   // drains stage(nxt) + all reads of cur, both wavesets
    }

    // ---- epilogue: score[row] += sum_col tanh(acc + qb[col]) * w2[col] ----
    // C/D: col = n0 + wc*64 + nf*16 + lr, row = m0 + wr*128 + mf*16 + lk*4 + r.
    const int bq = m0 >> 10;                       // 256 | 1024 -> single batch
    const float* qbb = qb + (size_t)bq * Hh;
#pragma unroll
    for (int mf = 0; mf < 8; ++mf) {
        float s0 = 0.f, s1 = 0.f, s2 = 0.f, s3 = 0.f;
#pragma unroll
        for (int nf = 0; nf < 4; ++nf) {
            int col = n0 + wc * 64 + nf * 16 + lr;
            float wvw = w2[col];
            float qv = qbb[col];
            s0 += tanhf(acc[mf][nf][0] + qv) * wvw;
            s1 += tanhf(acc[mf][nf][1] + qv) * wvw;
            s2 += tanhf(acc[mf][nf][2] + qv) * wvw;
            s3 += tanhf(acc[mf][nf][3] + qv) * wvw;
        }
#pragma unroll
        for (int off = 8; off; off >>= 1) {
            s0 += __shfl_xor(s0, off, 16);
            s1 += __shfl_xor(s1, off, 16);
            s2 += __shfl_xor(s2, off, 16);
            s3 += __shfl_xor(s3, off, 16);
        }
        if (lr == 0) {
            int row = m0 + wr * 128 + mf * 16 + lk * 4;
            atomicAdd(&score[row + 0], s0);
            atomicAdd(&score[row + 1], s1);
            atomicAdd(&score[row + 2], s2);
            atomicAdd(&score[row + 3], s3);
        }
    }
}

// ---------------------------------------------------------------------------
// scan: p = sigmoid(score + b2, masked, + noise); att_l = p_l * prod_{i<l}(1-p_i)
// ---------------------------------------------------------------------------
__global__ __launch_bounds__(64) void scan_kernel(const float* __restrict__ score,
                                                  const int* __restrict__ mask,
                                                  const float* __restrict__ noise,
                                                  const float* __restrict__ b2p,
                                                  float* __restrict__ att) {
    int b = blockIdx.x;
    int lane = threadIdx.x;
    float b2 = b2p[0];
    int base = b * Ll + lane * 16;

    float p[16], q[16];
    float run = 1.f;
#pragma unroll
    for (int j = 0; j < 16; ++j) {
        int l = base + j;
        float s = score[l] + b2;
        if (mask[l] == 0) s = NEG_NUM;
        s += noise[l];
        float pv = 1.f / (1.f + expf(-s));
        p[j] = pv;
        run *= (1.f - pv);
        q[j] = run;
    }
    float incl = run;
#pragma unroll
    for (int off = 1; off < 64; off <<= 1) {
        float v = __shfl_up(incl, off, 64);
        if (lane >= off) incl *= v;
    }
    float excl = __shfl_up(incl, 1, 64);
    if (lane == 0) excl = 1.f;
#pragma unroll
    for (int j = 0; j < 16; ++j) {
        float P = excl * (j == 0 ? 1.f : q[j - 1]);
        att[base + j] = p[j] * P;
    }
}

// ---------------------------------------------------------------------------
// expected_ctx[b,c] = sum_l att[b,l] * ctx[b,l,c]  (swz bf16 ctxb, 4 c/thread)
// ---------------------------------------------------------------------------
__global__ __launch_bounds__(256) void ectx_bf16_kernel(const unsigned short* __restrict__ ctxb,
                                                        const float* __restrict__ att,
                                                        float* __restrict__ out) {
    int b = blockIdx.z;
    int c4 = threadIdx.x;                 // c = c4*4
    int l0 = blockIdx.y * 128;
    const unsigned short* cb = ctxb + ((size_t)b * Ll + l0) * DC;
    const float* ab = att + (size_t)b * Ll + l0;
    const int c = c4 * 4;
    float a0 = 0.f, a1 = 0.f, a2 = 0.f, a3 = 0.f;
    for (int l = 0; l < 128; ++l) {
        float av = ab[l];
        int cs = c ^ ((l & 7) << 3);
        ushort4 v = *(const ushort4*)(cb + (size_t)l * DC + cs);
        a0 += av * bfu(v.x); a1 += av * bfu(v.y);
        a2 += av * bfu(v.z); a3 += av * bfu(v.w);
    }
    float* o = out + (size_t)b * DC + c;
    atomicAdd(o + 0, a0); atomicAdd(o + 1, a1);
    atomicAdd(o + 2, a2); atomicAdd(o + 3, a3);
}

// ---------------------------------------------------------------------------
extern "C" void kernel_launch(void* const* d_in, const int* in_sizes, int n_in,
                              void* d_out, int out_size, void* d_ws, size_t ws_size,
                              hipStream_t stream) {
    const float* ctx   = (const float*)d_in[0];
    const float* query = (const float*)d_in[1];
    const int*   mask  = (const int*)d_in[2];
    const float* noise = (const float*)d_in[3];
    const float* W1    = (const float*)d_in[4];
    const float* b1    = (const float*)d_in[5];
    const float* w2    = (const float*)d_in[6];
    const float* b2    = (const float*)d_in[7];

    float* out_ctx = (float*)d_out;                 // [B, DC]
    float* out_att = (float*)d_out + Bb * DC;       // [B, L]

    char* ws = (char*)d_ws;
    float* score = (float*)ws;                                   // 131072 B
    float* qb    = (float*)(ws + 131072);                        //  65536 B
    unsigned short* w1t  = (unsigned short*)(ws + 196608);       // 1 MiB
    unsigned short* ctxb = (unsigned short*)(ws + 1245184);      // 64 MiB

    // w1t transpose-cvt (swz) + zeros + qb + ctx->bf16 (one kernel)
    prep_kernel<<<18816, 256, 0, stream>>>(W1, query, b1, ctx, w1t, qb, score, out_ctx, ctxb);

    // 256x256 double-buffered MFMA GEMM + tanh + w2 -> score
    gemm_mfma<<<dim3(Hh / 256, (Bb * Ll) / 256), 512, 0, stream>>>(ctxb, w1t, qb, w2, score);

    // sigmoid/mask/noise/scan -> att (second output)
    scan_kernel<<<Bb, 64, 0, stream>>>(score, mask, noise, b2, out_att);

    // expected_ctx = att @ ctx (swz bf16 ctxb, L3-resident)
    ectx_bf16_kernel<<<dim3(1, Ll / 128, Bb), 256, 0, stream>>>(ctxb, out_att, out_ctx);
}

// Round 11
// 99.380 us; speedup vs baseline: 1.4334x; 1.0118x over previous
//
#include <hip/hip_runtime.h>
#include <hip/hip_bf16.h>
#include <math.h>

// Problem constants
constexpr int Bb = 32;
constexpr int Ll = 1024;
constexpr int DC = 1024;
constexpr int DQ = 1024;
constexpr int Hh = 512;
#define NEG_NUM -10000.0f

typedef __attribute__((ext_vector_type(8))) short bf16x8;
typedef __attribute__((ext_vector_type(4))) float f32x4;

#define GLOAD_LDS16(g, l)                                                  \
    __builtin_amdgcn_global_load_lds(                                      \
        (const __attribute__((address_space(1))) void*)(g),                \
        (__attribute__((address_space(3))) void*)(l), 16, 0, 0)

__device__ inline unsigned short f2bf(float f) {           // RNE f32->bf16
    unsigned int x = __float_as_uint(f);
    unsigned int r = (x + 0x7FFFu + ((x >> 16) & 1u)) >> 16;
    return (unsigned short)r;
}
__device__ inline float bfu(unsigned short u) {            // bf16 bits -> f32 (exact)
    return __uint_as_float(((unsigned int)u) << 16);
}

// SWIZZLE (verified R8-R10, conflicts=0): bf16 buffers store element (row, k)
// at k ^ ((row&7)<<3) within each 64-elem k-block; consumers XOR on read.

// ---------------------------------------------------------------------------
// prep, 18816 blocks (verified R9/R10):
//   [0,2048):        W1[:DC] -> w1t bf16 (512x1024 transposed, swz)
//   [2048,2176):     zero out_ctx AND score
//   [2176,2432):     qb[b,h] = query[b,:] @ W1[DC:,h] + b1[h]
//   [2432,18816):    ctx fp32 -> ctxb bf16 (swizzled store), 8 elem/thread
// ---------------------------------------------------------------------------
__global__ __launch_bounds__(256) void prep_kernel(const float* __restrict__ W1,
                                                   const float* __restrict__ query,
                                                   const float* __restrict__ b1,
                                                   const float* __restrict__ ctx,
                                                   unsigned short* __restrict__ w1t,
                                                   float* __restrict__ qb,
                                                   float* __restrict__ score,
                                                   float* __restrict__ out_ctx,
                                                   unsigned short* __restrict__ ctxb) {
    __shared__ float red[4][64];
    const int bid = blockIdx.x;
    if (bid < 2048) {
        int idx = bid * 256 + threadIdx.x;   // n*1024 + k
        int n = idx >> 10, k = idx & 1023;
        int ks = k ^ ((n & 7) << 3);
        w1t[(size_t)n * 1024 + ks] = f2bf(W1[(size_t)k * Hh + n]);
    } else if (bid < 2176) {
        int i = (bid - 2048) * 256 + threadIdx.x;
        out_ctx[i] = 0.f;
        score[i] = 0.f;
    } else if (bid < 2432) {
        const int qbid = bid - 2176;          // 0..255
        const int b  = qbid >> 3;
        const int hg = qbid & 7;
        const int hl = threadIdx.x & 63;
        const int j  = threadIdx.x >> 6;
        const int h  = hg * 64 + hl;
        const float* q = query + (size_t)b * DQ + j * 256;
        const float* w = W1 + (size_t)(DC + j * 256) * Hh + h;
        float a0 = 0.f, a1 = 0.f, a2 = 0.f, a3 = 0.f;
#pragma unroll 4
        for (int c = 0; c < 256; c += 4) {
            a0 += q[c + 0] * w[(size_t)(c + 0) * Hh];
            a1 += q[c + 1] * w[(size_t)(c + 1) * Hh];
            a2 += q[c + 2] * w[(size_t)(c + 2) * Hh];
            a3 += q[c + 3] * w[(size_t)(c + 3) * Hh];
        }
        red[j][hl] = (a0 + a1) + (a2 + a3);
        __syncthreads();
        if (j == 0)
            qb[(size_t)b * Hh + h] = red[0][hl] + red[1][hl] + red[2][hl] + red[3][hl] + b1[h];
    } else {
        size_t i = (size_t)((bid - 2432) * 256 + threadIdx.x) * 8;
        int row = (int)(i >> 10);
        int col = (int)(i & 1023);
        float4 v0 = *(const float4*)(ctx + i);
        float4 v1 = *(const float4*)(ctx + i + 4);
        union { unsigned short us[8]; uint4 v; } o;
        o.us[0] = f2bf(v0.x); o.us[1] = f2bf(v0.y); o.us[2] = f2bf(v0.z); o.us[3] = f2bf(v0.w);
        o.us[4] = f2bf(v1.x); o.us[5] = f2bf(v1.y); o.us[6] = f2bf(v1.z); o.us[7] = f2bf(v1.w);
        *(uint4*)(ctxb + ((size_t)row << 10) + (col ^ ((row & 7) << 3))) = o.v;
    }
}

// ---------------------------------------------------------------------------
// MFMA GEMM + tanh + w2 — 256x256, double-buffered, T4 counted-vmcnt loop.
//   512 thr / 8 waves (2 M x 4 N), acc 8x4, BK=64, 16 K-steps.
//   Loop (m201-style raw barriers, NEVER vmcnt(0) mid-loop):
//     s_barrier                       // compute(ks-1) readers done
//     STAGE(ks+1) -> buf[cur^1]      // 8 fire-and-forget gload_lds/thread
//     s_waitcnt vmcnt(8)             // drain STAGE(ks) ONLY; ks+1 in flight
//     s_barrier                      // cross-wave DMA visibility of STAGE(ks)
//     COMPUTE(buf[cur])              // 24 ds_read_b128 + 64 MFMA per wave
//   T1: bijective grid remap — the 2 n-blocks sharing an A-panel are 8 bids
//   apart -> same XCD -> A K-tiles L2-served for the sibling.
// ---------------------------------------------------------------------------
__global__ __launch_bounds__(512, 1) void gemm_mfma(const unsigned short* __restrict__ ctxb,
                                                    const unsigned short* __restrict__ w1t,
                                                    const float* __restrict__ qb,
                                                    const float* __restrict__ w2,
                                                    float* __restrict__ score) {
    __shared__ unsigned short lds[2 * 32768];      // 2 bufs x (A 32K + B 32K)

    // T1 remap: bid = 16*(y>>3) + 8*x + (y&7)  ->  x,y  (bijective, 256 blocks)
    const int bid = blockIdx.x;
    const int n0 = ((bid >> 3) & 1) * 256;
    const int m0 = (((bid >> 4) << 3) | (bid & 7)) * 256;

    const int tid = threadIdx.x;
    const int wv = tid >> 6, lane = tid & 63;
    const int wr = wv >> 2, wc = wv & 3;           // 2 M-waves x 4 N-waves
    const int lr = lane & 15, lk = lane >> 4;

    char* ldsB = (char*)lds;
    const char* ctxB = (const char*)ctxb;
    const char* w1tB = (const char*)w1t;

    const int srow = tid >> 3;                     // staging: 64 rows per issue
    const int scolb = (tid & 7) * 16;
    const int x = (lr & 7) << 4;                   // fragment read XOR

    f32x4 acc[8][4];
#pragma unroll
    for (int mf = 0; mf < 8; ++mf)
#pragma unroll
        for (int nf = 0; nf < 4; ++nf) acc[mf][nf] = (f32x4){0.f, 0.f, 0.f, 0.f};

    // ---- prologue: stage K-tile 0 into buf0 (8 issues/thread) ----
#pragma unroll
    for (int i = 0; i < 4; ++i) {
        int row = i * 64 + srow;
        GLOAD_LDS16(ctxB + (size_t)(m0 + row) * 2048 + scolb,
                    ldsB + i * 8192 + tid * 16);
        GLOAD_LDS16(w1tB + (size_t)(n0 + row) * 2048 + scolb,
                    ldsB + 32768 + i * 8192 + tid * 16);
    }

    // ---- main loop: 16 K-steps, counted-vmcnt pipeline ----
    for (int ks = 0; ks < 16; ++ks) {
        const int cur = ks & 1;
        char* bufc = ldsB + cur * 65536;

        __builtin_amdgcn_s_barrier();              // compute(ks-1) readers done
        if (ks < 15) {
            char* bufn = ldsB + (cur ^ 1) * 65536;
            const int kb = (ks + 1) * 128;         // byte offset of k0 in row
#pragma unroll
            for (int i = 0; i < 4; ++i) {
                int row = i * 64 + srow;
                GLOAD_LDS16(ctxB + (size_t)(m0 + row) * 2048 + kb + scolb,
                            bufn + i * 8192 + tid * 16);
                GLOAD_LDS16(w1tB + (size_t)(n0 + row) * 2048 + kb + scolb,
                            bufn + 32768 + i * 8192 + tid * 16);
            }
            asm volatile("s_waitcnt vmcnt(8)" ::: "memory");   // drain STAGE(ks)
        } else {
            asm volatile("s_waitcnt vmcnt(0)" ::: "memory");   // last tile
        }
        __builtin_amdgcn_sched_barrier(0);
        __builtin_amdgcn_s_barrier();              // STAGE(ks) visible to all

        // compute current buffer: 2 kk x (12 ds_read_b128, 32 MFMA)
#pragma unroll
        for (int kk = 0; kk < 2; ++kk) {
            const int colb = (kk * 64 + lk * 16) ^ x;
            bf16x8 a[8], bb[4];
#pragma unroll
            for (int nf = 0; nf < 4; ++nf)
                bb[nf] = *(const bf16x8*)(bufc + 32768 + (wc * 64 + nf * 16 + lr) * 128 + colb);
#pragma unroll
            for (int mf = 0; mf < 8; ++mf)
                a[mf] = *(const bf16x8*)(bufc + (wr * 128 + mf * 16 + lr) * 128 + colb);
#pragma unroll
            for (int mf = 0; mf < 8; ++mf)
#pragma unroll
                for (int nf = 0; nf < 4; ++nf)
                    acc[mf][nf] = __builtin_amdgcn_mfma_f32_16x16x32_bf16(a[mf], bb[nf], acc[mf][nf], 0, 0, 0);
        }
    }

    // ---- epilogue: score[row] += sum_col tanh(acc + qb[col]) * w2[col] ----
    // C/D: col = n0 + wc*64 + nf*16 + lr, row = m0 + wr*128 + mf*16 + lk*4 + r.
    const int bq = m0 >> 10;                       // 256 | 1024 -> single batch
    const float* qbb = qb + (size_t)bq * Hh;
#pragma unroll
    for (int mf = 0; mf < 8; ++mf) {
        float s0 = 0.f, s1 = 0.f, s2 = 0.f, s3 = 0.f;
#pragma unroll
        for (int nf = 0; nf < 4; ++nf) {
            int col = n0 + wc * 64 + nf * 16 + lr;
            float wvw = w2[col];
            float qv = qbb[col];
            s0 += tanhf(acc[mf][nf][0] + qv) * wvw;
            s1 += tanhf(acc[mf][nf][1] + qv) * wvw;
            s2 += tanhf(acc[mf][nf][2] + qv) * wvw;
            s3 += tanhf(acc[mf][nf][3] + qv) * wvw;
        }
#pragma unroll
        for (int off = 8; off; off >>= 1) {
            s0 += __shfl_xor(s0, off, 16);
            s1 += __shfl_xor(s1, off, 16);
            s2 += __shfl_xor(s2, off, 16);
            s3 += __shfl_xor(s3, off, 16);
        }
        if (lr == 0) {
            int row = m0 + wr * 128 + mf * 16 + lk * 4;
            atomicAdd(&score[row + 0], s0);
            atomicAdd(&score[row + 1], s1);
            atomicAdd(&score[row + 2], s2);
            atomicAdd(&score[row + 3], s3);
        }
    }
}

// ---------------------------------------------------------------------------
// scan: p = sigmoid(score + b2, masked, + noise); att_l = p_l * prod_{i<l}(1-p_i)
// ---------------------------------------------------------------------------
__global__ __launch_bounds__(64) void scan_kernel(const float* __restrict__ score,
                                                  const int* __restrict__ mask,
                                                  const float* __restrict__ noise,
                                                  const float* __restrict__ b2p,
                                                  float* __restrict__ att) {
    int b = blockIdx.x;
    int lane = threadIdx.x;
    float b2 = b2p[0];
    int base = b * Ll + lane * 16;

    float p[16], q[16];
    float run = 1.f;
#pragma unroll
    for (int j = 0; j < 16; ++j) {
        int l = base + j;
        float s = score[l] + b2;
        if (mask[l] == 0) s = NEG_NUM;
        s += noise[l];
        float pv = 1.f / (1.f + expf(-s));
        p[j] = pv;
        run *= (1.f - pv);
        q[j] = run;
    }
    float incl = run;
#pragma unroll
    for (int off = 1; off < 64; off <<= 1) {
        float v = __shfl_up(incl, off, 64);
        if (lane >= off) incl *= v;
    }
    float excl = __shfl_up(incl, 1, 64);
    if (lane == 0) excl = 1.f;
#pragma unroll
    for (int j = 0; j < 16; ++j) {
        float P = excl * (j == 0 ? 1.f : q[j - 1]);
        att[base + j] = p[j] * P;
    }
}

// ---------------------------------------------------------------------------
// expected_ctx[b,c] = sum_l att[b,l] * ctx[b,l,c]  (swz bf16 ctxb, 4 c/thread)
// ---------------------------------------------------------------------------
__global__ __launch_bounds__(256) void ectx_bf16_kernel(const unsigned short* __restrict__ ctxb,
                                                        const float* __restrict__ att,
                                                        float* __restrict__ out) {
    int b = blockIdx.z;
    int c4 = threadIdx.x;                 // c = c4*4
    int l0 = blockIdx.y * 128;
    const unsigned short* cb = ctxb + ((size_t)b * Ll + l0) * DC;
    const float* ab = att + (size_t)b * Ll + l0;
    const int c = c4 * 4;
    float a0 = 0.f, a1 = 0.f, a2 = 0.f, a3 = 0.f;
    for (int l = 0; l < 128; ++l) {
        float av = ab[l];
        int cs = c ^ ((l & 7) << 3);
        ushort4 v = *(const ushort4*)(cb + (size_t)l * DC + cs);
        a0 += av * bfu(v.x); a1 += av * bfu(v.y);
        a2 += av * bfu(v.z); a3 += av * bfu(v.w);
    }
    float* o = out + (size_t)b * DC + c;
    atomicAdd(o + 0, a0); atomicAdd(o + 1, a1);
    atomicAdd(o + 2, a2); atomicAdd(o + 3, a3);
}

// ---------------------------------------------------------------------------
extern "C" void kernel_launch(void* const* d_in, const int* in_sizes, int n_in,
                              void* d_out, int out_size, void* d_ws, size_t ws_size,
                              hipStream_t stream) {
    const float* ctx   = (const float*)d_in[0];
    const float* query = (const float*)d_in[1];
    const int*   mask  = (const int*)d_in[2];
    const float* noise = (const float*)d_in[3];
    const float* W1    = (const float*)d_in[4];
    const float* b1    = (const float*)d_in[5];
    const float* w2    = (const float*)d_in[6];
    const float* b2    = (const float*)d_in[7];

    float* out_ctx = (float*)d_out;                 // [B, DC]
    float* out_att = (float*)d_out + Bb * DC;       // [B, L]

    char* ws = (char*)d_ws;
    float* score = (float*)ws;                                   // 131072 B
    float* qb    = (float*)(ws + 131072);                        //  65536 B
    unsigned short* w1t  = (unsigned short*)(ws + 196608);       // 1 MiB
    unsigned short* ctxb = (unsigned short*)(ws + 1245184);      // 64 MiB

    // w1t transpose-cvt (swz) + zeros + qb + ctx->bf16 (one kernel)
    prep_kernel<<<18816, 256, 0, stream>>>(W1, query, b1, ctx, w1t, qb, score, out_ctx, ctxb);

    // 256x256 counted-vmcnt MFMA GEMM + tanh + w2 -> score
    gemm_mfma<<<256, 512, 0, stream>>>(ctxb, w1t, qb, w2, score);

    // sigmoid/mask/noise/scan -> att (second output)
    scan_kernel<<<Bb, 64, 0, stream>>>(score, mask, noise, b2, out_att);

    // expected_ctx = att @ ctx (swz bf16 ctxb, L3-resident)
    ectx_bf16_kernel<<<dim3(1, Ll / 128, Bb), 256, 0, stream>>>(ctxb, out_att, out_ctx);
}